// Round 5
// baseline (9277.539 us; speedup 1.0000x reference)
//
#include <hip/hip_runtime.h>
#include <hip/hip_cooperative_groups.h>

namespace cg = cooperative_groups;

#define NE 400
#define NIN 784
#define BB 512
#define TT 50
#define GRID 256

#define KC1 7          // gemm1 K-chunks over input dim (784 = 7*112)
#define KCH1 112
#define KC2 4          // gemm2 K-chunks over batch (512 = 4*128)
#define KCH2 128

constexpr float C_KE     = (float)(0.5 / 100.0);
constexpr float C_KI     = (float)(0.5 / 10.0);
constexpr float C_GSE    = 0.5f;
constexpr float C_GSI    = 0.25f;
constexpr float C_DECTH  = (float)(1.0 - 0.5 / 1e7);
constexpr float C_DEC1   = (float)(1.0 - 0.5 / 20.0);
constexpr float C_DEC2   = (float)(1.0 - 0.5 / 40.0);
constexpr float C_DECPRE = (float)(1.0 - 0.5 / 20.0);
constexpr float C_NUPRE  = (float)0.0001;
constexpr float C_NUPOST = 0.01f;

__global__ __launch_bounds__(256, 2) void k_persist(
    const float* __restrict__ x, const float* __restrict__ W0,
    float* __restrict__ wbuf0, float* __restrict__ wbuf1,
    float* __restrict__ dbb0, float* __restrict__ dbb1,
    float* __restrict__ dgp, float* __restrict__ part,
    float* __restrict__ A1, float* __restrict__ A2,
    float* __restrict__ tr, float* __restrict__ out)
{
    // persistent per-row LIF state: block bid owns batch rows bid and bid+256
    // slots: 0 g_ine, 1 g_ei, 2 g_ie, 3 Iie, 4 mem_e, 5 rc_e, 6 mem_i, 7 rc_i,
    //        8 theta, 9 tp1, 10 tp2. second row at offset NE.
    __shared__ float st[11][2 * NE];
    __shared__ float sA[16][68], sB[16][68], sC[16][68], sD[16][68];
    __shared__ float red[256];
    __shared__ float sred[4];

    cg::grid_group grid = cg::this_grid();
    const int lid = threadIdx.x;
    const int bid = blockIdx.x;
    const float4 z4 = make_float4(0.f, 0.f, 0.f, 0.f);

    // ---------- pre-phase: LDS state init + d0 = rowsum(W0)/78.4 (R1 tree order) ----
#pragma unroll
    for (int jj = 0; jj < 4; jj++) {
        int e = lid + jj * 256;
        if (e < 2 * NE) {
            st[0][e] = 0.f; st[1][e] = 0.f; st[2][e] = 0.f; st[3][e] = 0.f;
            st[4][e] = -65.f; st[5][e] = 0.f; st[6][e] = -60.f; st[7][e] = 0.f;
            st[8][e] = 20.f; st[9][e] = 0.f; st[10][e] = 0.f;
        }
    }
    for (int j = bid; j < NE; j += GRID) {
        float s = 0.f;
        if (lid < 196) {
            float4 w = *(const float4*)&W0[j * NIN + lid * 4];
            s = w.x + w.y + w.z + w.w;
        }
        red[lid] = s;
        __syncthreads();
        for (int off = 128; off > 0; off >>= 1) {
            if (lid < off) red[lid] += red[lid + off];
            __syncthreads();
        }
        if (lid == 0) dbb0[j] = red[0] / 78.4f;
        __syncthreads();
    }
    grid.sync();

    for (int t = 0; t < TT; t++) {
        const float* xt = x + (size_t)t * BB * NIN;
        const float* Wt = (t == 0) ? W0 : ((t & 1) ? wbuf1 : wbuf0);
        const float* dt = (t & 1) ? dbb1 : dbb0;
        float* Wn = (t & 1) ? wbuf0 : wbuf1;   // W_{t+1}
        float* dn = (t & 1) ? dbb0 : dbb1;     // d_{t+1}

        // ---------- phase A: gemm1 partials (392 jobs) + pre-trace (512 jobs) -------
        for (int j = bid; j < 392 + BB; j += GRID) {
            if (j < 392) {
                int jz = j / 56, rr = j % 56;
                int jy = rr / 7, jx = rr % 7;
                int e0 = jx * 64, b0 = jy * 64, kb = jz * KCH1;
                int tx = lid & 15, ty = lid >> 4;
                int r = lid >> 2, cb = (lid & 3) * 4;
                bool ev = (e0 + r) < NE;
                float acc[4][4];
#pragma unroll
                for (int a = 0; a < 4; a++)
#pragma unroll
                    for (int c = 0; c < 4; c++) acc[a][c] = 0.f;
                float4 xv = *(const float4*)&xt[(b0 + r) * NIN + kb + cb];
                float4 wv = ev ? *(const float4*)&Wt[(e0 + r) * NIN + kb + cb] : z4;
                for (int kt = 0; kt < KCH1 / 16; kt++) {
                    sA[cb + 0][r] = xv.x; sA[cb + 1][r] = xv.y;
                    sA[cb + 2][r] = xv.z; sA[cb + 3][r] = xv.w;
                    sB[cb + 0][r] = wv.x; sB[cb + 1][r] = wv.y;
                    sB[cb + 2][r] = wv.z; sB[cb + 3][r] = wv.w;
                    __syncthreads();
                    if (kt < KCH1 / 16 - 1) {
                        int k0 = kb + (kt + 1) * 16;
                        xv = *(const float4*)&xt[(b0 + r) * NIN + k0 + cb];
                        wv = ev ? *(const float4*)&Wt[(e0 + r) * NIN + k0 + cb] : z4;
                    }
#pragma unroll
                    for (int k = 0; k < 16; k++) {
                        float4 av = *(const float4*)&sA[k][ty * 4];
                        float4 bv = *(const float4*)&sB[k][tx * 4];
                        float a[4] = {av.x, av.y, av.z, av.w};
                        float b[4] = {bv.x, bv.y, bv.z, bv.w};
#pragma unroll
                        for (int p = 0; p < 4; p++)
#pragma unroll
                            for (int q = 0; q < 4; q++) acc[p][q] += a[p] * b[q];
                    }
                    __syncthreads();
                }
                if (e0 + tx * 4 < NE) {
                    float* basep = dgp + (size_t)jz * BB * NE;
#pragma unroll
                    for (int p = 0; p < 4; p++) {
                        float4 v = make_float4(acc[p][0], acc[p][1], acc[p][2], acc[p][3]);
                        *(float4*)&basep[(b0 + ty * 4 + p) * NE + e0 + tx * 4] = v;
                    }
                }
            } else {
                int b = j - 392;
                if (lid < 196) {
                    int o = b * NIN + lid * 4;
                    float4 xv = *(const float4*)&xt[o];
                    float4 res;
                    if (t == 0) {
                        res = xv;
                    } else {
                        float4 tv = *(const float4*)&tr[o];
                        res.x = (xv.x > 0.9f) ? 1.f : tv.x * C_DECPRE;
                        res.y = (xv.y > 0.9f) ? 1.f : tv.y * C_DECPRE;
                        res.z = (xv.z > 0.9f) ? 1.f : tv.z * C_DECPRE;
                        res.w = (xv.w > 0.9f) ? 1.f : tv.w * C_DECPRE;
                    }
                    *(float4*)&tr[o] = res;
                }
            }
        }
        grid.sync();

        // ---------- phase B: LIF/mid — block handles rows bid and bid+256 ----------
#pragma unroll
        for (int rr = 0; rr < 2; rr++) {
            int b = bid + rr * 256;
            int so = rr * NE;
            float me_[2], spk_[2], si_[2];
            float Spart = 0.f;
#pragma unroll
            for (int jj = 0; jj < 2; jj++) {
                int e = lid + jj * 256;
                me_[jj] = 0.f; spk_[jj] = 0.f; si_[jj] = 0.f;
                if (e < NE) {
                    float dsum = 0.f;
#pragma unroll
                    for (int c = 0; c < KC1; c++)
                        dsum += dgp[(size_t)c * BB * NE + b * NE + e];
                    float dg = dsum / dt[e];
                    float g1 = st[0][so + e], me = st[4][so + e], re = st[5][so + e];
                    float th = st[8][so + e], Ii = st[3][so + e];
                    float I_in = g1 * (0.f - me);
                    g1 = g1 + (dg - g1) * C_GSE;
                    bool act = re <= 0.f;
                    float I = I_in + Ii;
                    if (act) me = me + ((-65.f - me) + I) * C_KE;
                    re = fmaxf(re - 0.5f, 0.f);
                    float thr = -72.f + th;
                    float spk = (act && me > thr) ? 1.f : 0.f;
                    if (spk > 0.f) { me = -65.f; re = 5.f; }
                    float dgei = spk * 10.4f;
                    float g2 = st[1][so + e], mi = st[6][so + e], ri = st[7][so + e];
                    float I_ei = g2 * (0.f - mi);
                    g2 = g2 + (dgei - g2) * C_GSE;
                    bool ai = ri <= 0.f;
                    if (ai) mi = mi + ((-60.f - mi) + I_ei) * C_KI;
                    ri = fmaxf(ri - 0.5f, 0.f);
                    float si = (ai && mi > -40.f) ? 1.f : 0.f;
                    if (si > 0.f) { mi = -45.f; ri = 2.f; }
                    st[0][so + e] = g1; st[1][so + e] = g2; st[5][so + e] = re;
                    st[6][so + e] = mi; st[7][so + e] = ri;
                    me_[jj] = me; spk_[jj] = spk; si_[jj] = si;
                    Spart += si;
                }
            }
            float v = Spart;
            for (int o = 32; o > 0; o >>= 1) v += __shfl_down(v, o, 64);
            if ((lid & 63) == 0) sred[lid >> 6] = v;
            __syncthreads();
            float S = (sred[0] + sred[1]) + (sred[2] + sred[3]);  // integer: exact
#pragma unroll
            for (int jj = 0; jj < 2; jj++) {
                int e = lid + jj * 256;
                if (e < NE) {
                    float me = me_[jj], spk = spk_[jj], si = si_[jj];
                    float g3 = st[2][so + e];
                    float Iie_new = g3 * (-100.f - me);
                    float dgie = 17.f * (S - si);
                    g3 = g3 + (dgie - g3) * C_GSI;
                    float th = st[8][so + e] * C_DECTH + 0.05f * spk;
                    float r1 = st[9][so + e] * C_DEC1;
                    float r2 = st[10][so + e] * C_DEC2;
                    bool fired = spk > 0.9f;
                    A1[b * NE + e] = r1;
                    A2[b * NE + e] = spk * r2;
                    st[9][so + e] = fired ? 1.f : r1;
                    st[10][so + e] = fired ? 1.f : r2;
                    st[2][so + e] = g3; st[3][so + e] = Iie_new;
                    st[4][so + e] = me; st[8][so + e] = th;
                    out[(size_t)t * BB * NE + b * NE + e] = spk;
                }
            }
            __syncthreads();   // sred reused by next row
        }
        grid.sync();

        if (t < TT - 1) {
            // ---------- phase C: gemm2 partials (364 jobs) ----------
            for (int j = bid; j < 364; j += GRID) {
                int jz = j / 91, rj = j % 91;
                int jy = rj / 13, jx = rj % 13;
                int i0 = jx * 64, e0 = jy * 64, bb0 = jz * KCH2;
                int tx = lid & 15, ty = lid >> 4;
                int r = lid >> 4, cb = (lid & 15) * 4;
                float s1[4][4], s2[4][4];
#pragma unroll
                for (int a = 0; a < 4; a++)
#pragma unroll
                    for (int c = 0; c < 4; c++) { s1[a][c] = 0.f; s2[a][c] = 0.f; }
                float4 v1, v2, xv, tv;
                auto ld = [&](int bt) {
                    int b0 = bb0 + bt * 16;
                    if (e0 + cb < NE) {
                        v1 = *(const float4*)&A1[(b0 + r) * NE + e0 + cb];
                        v2 = *(const float4*)&A2[(b0 + r) * NE + e0 + cb];
                    } else { v1 = z4; v2 = z4; }
                    if (i0 + cb < NIN) {
                        xv = *(const float4*)&xt[(b0 + r) * NIN + i0 + cb];
                        tv = *(const float4*)&tr[(b0 + r) * NIN + i0 + cb];
                    } else { xv = z4; tv = z4; }
                };
                ld(0);
                for (int bt = 0; bt < KCH2 / 16; bt++) {
                    *(float4*)&sA[r][cb] = v1;
                    *(float4*)&sB[r][cb] = v2;
                    *(float4*)&sC[r][cb] = xv;
                    *(float4*)&sD[r][cb] = tv;
                    __syncthreads();
                    if (bt < KCH2 / 16 - 1) ld(bt + 1);
#pragma unroll
                    for (int k = 0; k < 16; k++) {
                        float4 a1v = *(const float4*)&sA[k][ty * 4];
                        float4 a2v = *(const float4*)&sB[k][ty * 4];
                        float4 xvv = *(const float4*)&sC[k][tx * 4];
                        float4 tvv = *(const float4*)&sD[k][tx * 4];
                        float a1[4] = {a1v.x, a1v.y, a1v.z, a1v.w};
                        float a2[4] = {a2v.x, a2v.y, a2v.z, a2v.w};
                        float xx[4] = {xvv.x, xvv.y, xvv.z, xvv.w};
                        float tt[4] = {tvv.x, tvv.y, tvv.z, tvv.w};
#pragma unroll
                        for (int p = 0; p < 4; p++)
#pragma unroll
                            for (int q = 0; q < 4; q++) {
                                s1[p][q] += a1[p] * xx[q];
                                s2[p][q] += a2[p] * tt[q];
                            }
                    }
                    __syncthreads();
                }
                if (e0 + ty * 4 < NE && i0 + tx * 4 < NIN) {
                    float* basep = part + (size_t)jz * NE * NIN;
#pragma unroll
                    for (int p = 0; p < 4; p++) {
                        float4 v = make_float4(
                            C_NUPRE * s1[p][0] + C_NUPOST * s2[p][0],
                            C_NUPRE * s1[p][1] + C_NUPOST * s2[p][1],
                            C_NUPRE * s1[p][2] + C_NUPOST * s2[p][2],
                            C_NUPRE * s1[p][3] + C_NUPOST * s2[p][3]);
                        *(float4*)&basep[(e0 + ty * 4 + p) * NIN + i0 + tx * 4] = v;
                    }
                }
            }
            grid.sync();

            // ---------- phase D: W_{t+1} = clip(W_t/d + sum part), d_{t+1} (tree) ---
            for (int j = bid; j < NE; j += GRID) {
                float dv = dt[j];
                float s = 0.f;
                if (lid < 196) {
                    int o = j * NIN + lid * 4;
                    float4 w = *(const float4*)&Wt[o];
                    float4 a = make_float4(w.x / dv, w.y / dv, w.z / dv, w.w / dv);
#pragma unroll
                    for (int c = 0; c < KC2; c++) {
                        float4 pp = *(const float4*)&part[(size_t)c * NE * NIN + o];
                        a.x += pp.x; a.y += pp.y; a.z += pp.z; a.w += pp.w;
                    }
                    a.x = fminf(fmaxf(a.x, 0.f), 1.f);
                    a.y = fminf(fmaxf(a.y, 0.f), 1.f);
                    a.z = fminf(fmaxf(a.z, 0.f), 1.f);
                    a.w = fminf(fmaxf(a.w, 0.f), 1.f);
                    *(float4*)&Wn[o] = a;
                    s = a.x + a.y + a.z + a.w;
                }
                red[lid] = s;
                __syncthreads();
                for (int off = 128; off > 0; off >>= 1) {
                    if (lid < off) red[lid] += red[lid + off];
                    __syncthreads();
                }
                if (lid == 0) dn[j] = red[0] / 78.4f;
                __syncthreads();
            }
            grid.sync();
        }
    }
}

extern "C" void kernel_launch(void* const* d_in, const int* in_sizes, int n_in,
                              void* d_out, int out_size, void* d_ws, size_t ws_size,
                              hipStream_t stream) {
    const float* x     = (const float*)d_in[0];  // (50, 512, 784)
    const float* W_ine = (const float*)d_in[1];  // (400, 784)

    float* p = (float*)d_ws;
    float* wbuf0 = p; p += NE * NIN;
    float* wbuf1 = p; p += NE * NIN;
    float* dbb0  = p; p += NE;
    float* dbb1  = p; p += NE;
    float* dgp   = p; p += (size_t)KC1 * BB * NE;
    float* part  = p; p += (size_t)KC2 * NE * NIN;
    float* A1    = p; p += BB * NE;
    float* A2    = p; p += BB * NE;
    float* tr    = p; p += BB * NIN;
    float* out   = (float*)d_out;

    void* args[] = {(void*)&x, (void*)&W_ine, (void*)&wbuf0, (void*)&wbuf1,
                    (void*)&dbb0, (void*)&dbb1, (void*)&dgp, (void*)&part,
                    (void*)&A1, (void*)&A2, (void*)&tr, (void*)&out};
    hipLaunchCooperativeKernel((void*)k_persist, dim3(GRID), dim3(256), args, 0, stream);
}

// Round 6
// 2231.546 us; speedup vs baseline: 4.1574x; 4.1574x over previous
//
#include <hip/hip_runtime.h>

#define NE 400
#define NIN 784
#define BB 512
#define TT 50

#define KC1 7          // gemm1 K-chunks over input dim (784 = 7*112)
#define KCH1 112
#define KC2 8          // gemm2 K-chunks over concat batch (1024 = 8*128)
#define KCH2 128

constexpr float C_KE     = (float)(0.5 / 100.0);
constexpr float C_KI     = (float)(0.5 / 10.0);
constexpr float C_GSE    = 0.5f;
constexpr float C_GSI    = 0.25f;
constexpr float C_DECTH  = (float)(1.0 - 0.5 / 1e7);
constexpr float C_DEC1   = (float)(1.0 - 0.5 / 20.0);
constexpr float C_DEC2   = (float)(1.0 - 0.5 / 40.0);
constexpr float C_DECPRE = (float)(1.0 - 0.5 / 20.0);
constexpr float C_NUPRE  = (float)0.0001;
constexpr float C_NUPOST = 0.01f;

__global__ void k_init(float* g_ine, float* g_ei, float* g_ie, float* Iie,
                       float* mem_e, float* rc_e, float* mem_i, float* rc_i,
                       float* theta, float* tp1, float* tp2) {
    int i = blockIdx.x * blockDim.x + threadIdx.x;
    if (i < BB * NE) {
        g_ine[i] = 0.f; g_ei[i] = 0.f; g_ie[i] = 0.f; Iie[i] = 0.f;
        mem_e[i] = -65.0f; rc_e[i] = 0.f;
        mem_i[i] = -60.0f; rc_i[i] = 0.f;
        theta[i] = 20.0f; tp1[i] = 0.f; tp2[i] = 0.f;
    }
}

// initial d[e] = rowsum(W)/78.4  (R1 tree order)
__global__ __launch_bounds__(256) void k_rowsum0(const float* __restrict__ W,
                                                 float* __restrict__ d) {
    int e = blockIdx.x, tid = threadIdx.x;
    __shared__ float red[256];
    float s = 0.f;
    if (tid < 196) {
        float4 w = *(const float4*)&W[e * NIN + tid * 4];
        s = w.x + w.y + w.z + w.w;
    }
    red[tid] = s;
    __syncthreads();
    for (int off = 128; off > 0; off >>= 1) {
        if (tid < off) red[tid] += red[tid + off];
        __syncthreads();
    }
    if (tid == 0) d[e] = red[0] / 78.4f;
}

// gemm1 partials: dgp[kc][b][e] = sum_{k in chunk} x[b,k]*W[e,k]  (NT)
// tile 64(b) x 128(e), per-thread 4x8 in two 64-col quadrants, K-tile 16
__global__ __launch_bounds__(256) void k_g1(const float* __restrict__ x,
                                            const float* __restrict__ W,
                                            float* __restrict__ dgp) {
    __shared__ float sA[16][68];    // [k][b 64]
    __shared__ float sB[16][132];   // [k][e 128]
    const int lid = threadIdx.x;
    const int tx = lid & 15, ty = lid >> 4;
    const int e0 = blockIdx.x * 128, b0 = blockIdx.y * 64;
    const int kb = blockIdx.z * KCH1;
    const int sr = lid >> 2;          // 0..63
    const int sj = (lid & 3) * 4;     // k-offset 0,4,8,12
    const float4 z4 = make_float4(0.f, 0.f, 0.f, 0.f);

    float acc[4][2][4];
#pragma unroll
    for (int p = 0; p < 4; p++)
#pragma unroll
        for (int h = 0; h < 2; h++)
#pragma unroll
            for (int q = 0; q < 4; q++) acc[p][h][q] = 0.f;

    float4 xv, wv0, wv1;
    auto ld = [&](int kt) {
        int k0 = kb + kt * 16;
        xv = *(const float4*)&x[(b0 + sr) * NIN + k0 + sj];
        int e1 = e0 + sr, e2 = e0 + 64 + sr;
        wv0 = (e1 < NE) ? *(const float4*)&W[e1 * NIN + k0 + sj] : z4;
        wv1 = (e2 < NE) ? *(const float4*)&W[e2 * NIN + k0 + sj] : z4;
    };

    ld(0);
    for (int kt = 0; kt < KCH1 / 16; kt++) {
        sA[sj + 0][sr] = xv.x; sA[sj + 1][sr] = xv.y;
        sA[sj + 2][sr] = xv.z; sA[sj + 3][sr] = xv.w;
        sB[sj + 0][sr] = wv0.x; sB[sj + 1][sr] = wv0.y;
        sB[sj + 2][sr] = wv0.z; sB[sj + 3][sr] = wv0.w;
        sB[sj + 0][64 + sr] = wv1.x; sB[sj + 1][64 + sr] = wv1.y;
        sB[sj + 2][64 + sr] = wv1.z; sB[sj + 3][64 + sr] = wv1.w;
        __syncthreads();
        if (kt < KCH1 / 16 - 1) ld(kt + 1);
#pragma unroll
        for (int k = 0; k < 16; k++) {
            float4 av = *(const float4*)&sA[k][ty * 4];
            float4 b0v = *(const float4*)&sB[k][tx * 4];
            float4 b1v = *(const float4*)&sB[k][64 + tx * 4];
            float a[4] = {av.x, av.y, av.z, av.w};
            float bq0[4] = {b0v.x, b0v.y, b0v.z, b0v.w};
            float bq1[4] = {b1v.x, b1v.y, b1v.z, b1v.w};
#pragma unroll
            for (int p = 0; p < 4; p++)
#pragma unroll
                for (int q = 0; q < 4; q++) {
                    acc[p][0][q] += a[p] * bq0[q];
                    acc[p][1][q] += a[p] * bq1[q];
                }
        }
        __syncthreads();
    }
    float* basep = dgp + (size_t)blockIdx.z * BB * NE;
    int c1 = e0 + tx * 4, c2 = e0 + 64 + tx * 4;
#pragma unroll
    for (int p = 0; p < 4; p++) {
        int row = b0 + ty * 4 + p;
        if (c1 < NE)
            *(float4*)&basep[row * NE + c1] =
                make_float4(acc[p][0][0], acc[p][0][1], acc[p][0][2], acc[p][0][3]);
        if (c2 < NE)
            *(float4*)&basep[row * NE + c2] =
                make_float4(acc[p][1][0], acc[p][1][1], acc[p][1][2], acc[p][1][3]);
    }
}

// fused: blocks [0,512) = per-batch LIF phase; [512,708) = pre-trace
// writes A1s = NU_PRE*ret1, A2s = NU_POST*(spike*ret2)  (nu folded for concat gemm2)
__global__ __launch_bounds__(512) void k_mid(const float* __restrict__ dgp,
                                             const float* __restrict__ d,
                                             const float* __restrict__ xt,
                                             float* __restrict__ tr, int t,
                                             float* g_ine, float* g_ei, float* g_ie,
                                             float* Iie, float* mem_e, float* rc_e,
                                             float* mem_i, float* rc_i, float* theta,
                                             float* tp1, float* tp2,
                                             float* __restrict__ A1s,
                                             float* __restrict__ A2s,
                                             float* __restrict__ out_t) {
    if (blockIdx.x >= BB) {
        int base = (blockIdx.x - BB) * 2048 + threadIdx.x * 4;
        float4 xv = *(const float4*)&xt[base];
        float4 o;
        if (t == 0) {
            o = xv;
        } else {
            float4 tv = *(const float4*)&tr[base];
            o.x = (xv.x > 0.9f) ? 1.f : tv.x * C_DECPRE;
            o.y = (xv.y > 0.9f) ? 1.f : tv.y * C_DECPRE;
            o.z = (xv.z > 0.9f) ? 1.f : tv.z * C_DECPRE;
            o.w = (xv.w > 0.9f) ? 1.f : tv.w * C_DECPRE;
        }
        *(float4*)&tr[base] = o;
        return;
    }
    int b = blockIdx.x;
    int e = threadIdx.x;
    __shared__ float red[8];
    int idx = b * NE + e;

    float spk_i = 0.f, spk_e = 0.f;
    float g1 = 0.f, me = 0.f, re = 0.f, th = 0.f, g2 = 0.f, mi = 0.f, ri = 0.f;

    if (e < NE) {
        float dg = 0.f;
#pragma unroll
        for (int c = 0; c < KC1; c++) dg += dgp[(size_t)c * BB * NE + idx];
        dg = dg / d[e];
        g1 = g_ine[idx]; me = mem_e[idx]; re = rc_e[idx];
        th = theta[idx];
        float Ii = Iie[idx];
        float I_in = g1 * (0.0f - me);
        g1 = g1 + (dg - g1) * C_GSE;
        bool act = (re <= 0.0f);
        float I = I_in + Ii;
        if (act) me = me + ((-65.0f - me) + I) * C_KE;
        re = fmaxf(re - 0.5f, 0.0f);
        float thr = -72.0f + th;
        spk_e = (act && (me > thr)) ? 1.0f : 0.0f;
        if (spk_e > 0.0f) { me = -65.0f; re = 5.0f; }
        float dgei = spk_e * 10.4f;
        g2 = g_ei[idx]; mi = mem_i[idx]; ri = rc_i[idx];
        float I_ei = g2 * (0.0f - mi);
        g2 = g2 + (dgei - g2) * C_GSE;
        bool ai = (ri <= 0.0f);
        if (ai) mi = mi + ((-60.0f - mi) + I_ei) * C_KI;
        ri = fmaxf(ri - 0.5f, 0.0f);
        spk_i = (ai && (mi > -40.0f)) ? 1.0f : 0.0f;
        if (spk_i > 0.0f) { mi = -45.0f; ri = 2.0f; }
    }
    float v = spk_i;
#pragma unroll
    for (int o = 32; o > 0; o >>= 1) v += __shfl_down(v, o, 64);
    if ((e & 63) == 0) red[e >> 6] = v;
    __syncthreads();
    float S = ((red[0] + red[1]) + (red[2] + red[3])) +
              ((red[4] + red[5]) + (red[6] + red[7]));   // integer-valued: exact
    if (e < NE) {
        float dgie = 17.0f * (S - spk_i);
        float g3 = g_ie[idx];
        float Iie_new = g3 * (-100.0f - me);
        g3 = g3 + (dgie - g3) * C_GSI;
        float th2 = th * C_DECTH + 0.05f * spk_e;
        float r1 = tp1[idx] * C_DEC1;
        float r2 = tp2[idx] * C_DEC2;
        bool fired = spk_e > 0.9f;
        A1s[idx] = C_NUPRE * r1;
        A2s[idx] = C_NUPOST * (spk_e * r2);
        tp1[idx] = fired ? 1.0f : r1;
        tp2[idx] = fired ? 1.0f : r2;
        g_ine[idx] = g1; g_ei[idx] = g2; g_ie[idx] = g3; Iie[idx] = Iie_new;
        mem_e[idx] = me; rc_e[idx] = re; mem_i[idx] = mi; rc_i[idx] = ri;
        theta[idx] = th2;
        out_t[idx] = spk_e;
    }
}

// gemm2 concat: part[c][e][i] = sum_{k in chunk} At[k,e]*Xt[k,i]
// At = [NU_PRE*A1 ; NU_POST*A2spk] (1024 x 400), Xt = [x ; tr] (1024 x 784)
// tile 64(e) x 128(i), per-thread 4x8 quadrants, K-tile 16; no transpose staging
__global__ __launch_bounds__(256) void k_g2(const float* __restrict__ A1s,
                                            const float* __restrict__ A2s,
                                            const float* __restrict__ x,
                                            const float* __restrict__ tr,
                                            float* __restrict__ part) {
    __shared__ float sA[16][68];    // [k][e 64]
    __shared__ float sB[16][132];   // [k][i 128]
    const int lid = threadIdx.x;
    const int tx = lid & 15, ty = lid >> 4;
    const int e0 = blockIdx.x * 64, i0 = blockIdx.y * 128;
    const int kb = blockIdx.z * KCH2;
    const int kr = lid >> 4;            // 0..15 (k row)
    const int jc = (lid & 15) * 4;      // col offset 0..60
    const float4 z4 = make_float4(0.f, 0.f, 0.f, 0.f);

    float acc[4][2][4];
#pragma unroll
    for (int p = 0; p < 4; p++)
#pragma unroll
        for (int h = 0; h < 2; h++)
#pragma unroll
            for (int q = 0; q < 4; q++) acc[p][h][q] = 0.f;

    float4 av_, bv0_, bv1_;
    auto ld = [&](int kt) {
        int gb = kb + kt * 16 + kr;
        int ec = e0 + jc;
        if (ec < NE)
            av_ = (gb < BB) ? *(const float4*)&A1s[gb * NE + ec]
                            : *(const float4*)&A2s[(gb - BB) * NE + ec];
        else av_ = z4;
        const float* src; int rb;
        if (gb < BB) { src = x; rb = gb; } else { src = tr; rb = gb - BB; }
        int c1 = i0 + jc, c2 = i0 + 64 + jc;
        bv0_ = (c1 < NIN) ? *(const float4*)&src[rb * NIN + c1] : z4;
        bv1_ = (c2 < NIN) ? *(const float4*)&src[rb * NIN + c2] : z4;
    };

    ld(0);
    for (int kt = 0; kt < KCH2 / 16; kt++) {
        *(float4*)&sA[kr][jc] = av_;
        *(float4*)&sB[kr][jc] = bv0_;
        *(float4*)&sB[kr][64 + jc] = bv1_;
        __syncthreads();
        if (kt < KCH2 / 16 - 1) ld(kt + 1);
#pragma unroll
        for (int k = 0; k < 16; k++) {
            float4 av = *(const float4*)&sA[k][ty * 4];
            float4 b0v = *(const float4*)&sB[k][tx * 4];
            float4 b1v = *(const float4*)&sB[k][64 + tx * 4];
            float a[4] = {av.x, av.y, av.z, av.w};
            float bq0[4] = {b0v.x, b0v.y, b0v.z, b0v.w};
            float bq1[4] = {b1v.x, b1v.y, b1v.z, b1v.w};
#pragma unroll
            for (int p = 0; p < 4; p++)
#pragma unroll
                for (int q = 0; q < 4; q++) {
                    acc[p][0][q] += a[p] * bq0[q];
                    acc[p][1][q] += a[p] * bq1[q];
                }
        }
        __syncthreads();
    }
    float* basep = part + (size_t)blockIdx.z * NE * NIN;
    int c1 = i0 + tx * 4, c2 = i0 + 64 + tx * 4;
#pragma unroll
    for (int p = 0; p < 4; p++) {
        int row = e0 + ty * 4 + p;
        if (row < NE) {
            if (c1 < NIN)
                *(float4*)&basep[row * NIN + c1] =
                    make_float4(acc[p][0][0], acc[p][0][1], acc[p][0][2], acc[p][0][3]);
            if (c2 < NIN)
                *(float4*)&basep[row * NIN + c2] =
                    make_float4(acc[p][1][0], acc[p][1][1], acc[p][1][2], acc[p][1][3]);
        }
    }
}

// W[e,i] = clip(W[e,i]/d[e] + sum_c part[c][e,i], 0, 1); d[e] = rowsum(W_new)/78.4
__global__ __launch_bounds__(256) void k_wup(float* __restrict__ W,
                                             const float* __restrict__ part,
                                             float* __restrict__ d) {
    int e = blockIdx.x, tid = threadIdx.x;
    __shared__ float red[256];
    float dv = d[e];
    float s = 0.f;
    if (tid < 196) {
        int off = e * NIN + tid * 4;
        float4 w = *(const float4*)&W[off];
        float4 acc = make_float4(w.x / dv, w.y / dv, w.z / dv, w.w / dv);
#pragma unroll
        for (int c = 0; c < KC2; c++) {
            float4 p = *(const float4*)&part[(size_t)c * NE * NIN + off];
            acc.x += p.x; acc.y += p.y; acc.z += p.z; acc.w += p.w;
        }
        acc.x = fminf(fmaxf(acc.x, 0.f), 1.f);
        acc.y = fminf(fmaxf(acc.y, 0.f), 1.f);
        acc.z = fminf(fmaxf(acc.z, 0.f), 1.f);
        acc.w = fminf(fmaxf(acc.w, 0.f), 1.f);
        *(float4*)&W[off] = acc;
        s = acc.x + acc.y + acc.z + acc.w;
    }
    red[tid] = s;
    __syncthreads();
    for (int off = 128; off > 0; off >>= 1) {
        if (tid < off) red[tid] += red[tid + off];
        __syncthreads();
    }
    if (tid == 0) d[e] = red[0] / 78.4f;
}

extern "C" void kernel_launch(void* const* d_in, const int* in_sizes, int n_in,
                              void* d_out, int out_size, void* d_ws, size_t ws_size,
                              hipStream_t stream) {
    const float* x     = (const float*)d_in[0];  // (50, 512, 784)
    const float* W_ine = (const float*)d_in[1];  // (400, 784)

    float* p = (float*)d_ws;
    float* W_cur = p; p += NE * NIN;
    float* dbuf  = p; p += NE;
    float* dgp   = p; p += (size_t)KC1 * BB * NE;
    float* part  = p; p += (size_t)KC2 * NE * NIN;
    float* A1s   = p; p += BB * NE;
    float* A2s   = p; p += BB * NE;
    float* g_ine = p; p += BB * NE;
    float* g_ei  = p; p += BB * NE;
    float* g_ie  = p; p += BB * NE;
    float* Iie   = p; p += BB * NE;
    float* mem_e = p; p += BB * NE;
    float* rc_e  = p; p += BB * NE;
    float* mem_i = p; p += BB * NE;
    float* rc_i  = p; p += BB * NE;
    float* theta = p; p += BB * NE;
    float* tp1   = p; p += BB * NE;
    float* tp2   = p; p += BB * NE;
    float* tr    = p; p += BB * NIN;

    hipMemcpyAsync(W_cur, W_ine, (size_t)NE * NIN * sizeof(float),
                   hipMemcpyDeviceToDevice, stream);
    k_init<<<(BB * NE + 255) / 256, 256, 0, stream>>>(g_ine, g_ei, g_ie, Iie, mem_e,
                                                      rc_e, mem_i, rc_i, theta, tp1, tp2);
    k_rowsum0<<<NE, 256, 0, stream>>>(W_cur, dbuf);

    for (int t = 0; t < TT; t++) {
        const float* xt = x + (size_t)t * BB * NIN;
        float* out_t = (float*)d_out + (size_t)t * BB * NE;
        k_g1<<<dim3(4, 8, KC1), 256, 0, stream>>>(xt, W_cur, dgp);
        k_mid<<<BB + 196, 512, 0, stream>>>(dgp, dbuf, xt, tr, t, g_ine, g_ei, g_ie,
                                            Iie, mem_e, rc_e, mem_i, rc_i, theta,
                                            tp1, tp2, A1s, A2s, out_t);
        if (t < TT - 1) {
            k_g2<<<dim3(7, 7, KC2), 256, 0, stream>>>(A1s, A2s, xt, tr, part);
            k_wup<<<NE, 256, 0, stream>>>(W_cur, part, dbuf);
        }
    }
}

// Round 7
// 2098.304 us; speedup vs baseline: 4.4214x; 1.0635x over previous
//
#include <hip/hip_runtime.h>

#define NE 400
#define NIN 784
#define BB 512
#define TT 50

#define KC1 14         // gemm1 K-chunks over input dim (784 = 14*56)
#define KCH1 56
#define KT1 8          // gemm1 inner k-tile
#define KC2 16         // gemm2 K-chunks over concat batch (1024 = 16*64)
#define KCH2 64

constexpr float C_KE     = (float)(0.5 / 100.0);
constexpr float C_KI     = (float)(0.5 / 10.0);
constexpr float C_GSE    = 0.5f;
constexpr float C_GSI    = 0.25f;
constexpr float C_DECTH  = (float)(1.0 - 0.5 / 1e7);
constexpr float C_DEC1   = (float)(1.0 - 0.5 / 20.0);
constexpr float C_DEC2   = (float)(1.0 - 0.5 / 40.0);
constexpr float C_DECPRE = (float)(1.0 - 0.5 / 20.0);
constexpr float C_NUPRE  = (float)0.0001;
constexpr float C_NUPOST = 0.01f;

__global__ void k_init(float* g_ine, float* g_ei, float* g_ie, float* Iie,
                       float* mem_e, float* rc_e, float* mem_i, float* rc_i,
                       float* theta, float* tp1, float* tp2) {
    int i = blockIdx.x * blockDim.x + threadIdx.x;
    if (i < BB * NE) {
        g_ine[i] = 0.f; g_ei[i] = 0.f; g_ie[i] = 0.f; Iie[i] = 0.f;
        mem_e[i] = -65.0f; rc_e[i] = 0.f;
        mem_i[i] = -60.0f; rc_i[i] = 0.f;
        theta[i] = 20.0f; tp1[i] = 0.f; tp2[i] = 0.f;
    }
}

// blocks [0,400): d0[e] = rowsum(W0)/78.4 ; blocks [400,596): tr = x(0)
__global__ __launch_bounds__(256) void k_pre(const float* __restrict__ W,
                                             float* __restrict__ d,
                                             const float* __restrict__ x0,
                                             float* __restrict__ tr) {
    int bid = blockIdx.x, tid = threadIdx.x;
    if (bid >= NE) {
        int base = (bid - NE) * 2048 + tid * 4;
        *(float4*)&tr[base] = *(const float4*)&x0[base];
        return;
    }
    __shared__ float red[256];
    float s = 0.f;
    if (tid < 196) {
        float4 w = *(const float4*)&W[bid * NIN + tid * 4];
        s = w.x + w.y + w.z + w.w;
    }
    red[tid] = s;
    __syncthreads();
    for (int off = 128; off > 0; off >>= 1) {
        if (tid < off) red[tid] += red[tid + off];
        __syncthreads();
    }
    if (tid == 0) d[bid] = red[0] / 78.4f;
}

// gemm1 partials: dgp[kc][b][e] = sum_{k in chunk} x[b,k]*W[e,k]  (NT)
// tile 64(b) x 128(e), per-thread 4x8 quadrants, k-tile 8, chunk 56
__global__ __launch_bounds__(256) void k_g1(const float* __restrict__ x,
                                            const float* __restrict__ W,
                                            float* __restrict__ dgp) {
    __shared__ float sA[KT1][68];    // [k][b 64]
    __shared__ float sB[KT1][132];   // [k][e 128]
    const int lid = threadIdx.x;
    const int tx = lid & 15, ty = lid >> 4;
    const int e0 = blockIdx.x * 128, b0 = blockIdx.y * 64;
    const int kb = blockIdx.z * KCH1;
    const int xr = lid >> 2, xc = (lid & 3) * 2;   // x stage: 64 rows x 8k, float2
    const int wr = lid >> 1, wc = (lid & 1) * 4;   // W stage: 128 rows x 8k, float4
    const bool wv_ok = (e0 + wr) < NE;
    const float4 z4 = make_float4(0.f, 0.f, 0.f, 0.f);

    float acc[4][2][4];
#pragma unroll
    for (int p = 0; p < 4; p++)
#pragma unroll
        for (int h = 0; h < 2; h++)
#pragma unroll
            for (int q = 0; q < 4; q++) acc[p][h][q] = 0.f;

    float2 xv;
    float4 wv;
    auto ld = [&](int kt) {
        int k0 = kb + kt * KT1;
        xv = *(const float2*)&x[(b0 + xr) * NIN + k0 + xc];
        wv = wv_ok ? *(const float4*)&W[(e0 + wr) * NIN + k0 + wc] : z4;
    };

    ld(0);
    for (int kt = 0; kt < KCH1 / KT1; kt++) {
        sA[xc + 0][xr] = xv.x; sA[xc + 1][xr] = xv.y;
        sB[wc + 0][wr] = wv.x; sB[wc + 1][wr] = wv.y;
        sB[wc + 2][wr] = wv.z; sB[wc + 3][wr] = wv.w;
        __syncthreads();
        if (kt < KCH1 / KT1 - 1) ld(kt + 1);
#pragma unroll
        for (int k = 0; k < KT1; k++) {
            float4 av = *(const float4*)&sA[k][ty * 4];
            float4 b0v = *(const float4*)&sB[k][tx * 4];
            float4 b1v = *(const float4*)&sB[k][64 + tx * 4];
            float a[4] = {av.x, av.y, av.z, av.w};
            float bq0[4] = {b0v.x, b0v.y, b0v.z, b0v.w};
            float bq1[4] = {b1v.x, b1v.y, b1v.z, b1v.w};
#pragma unroll
            for (int p = 0; p < 4; p++)
#pragma unroll
                for (int q = 0; q < 4; q++) {
                    acc[p][0][q] += a[p] * bq0[q];
                    acc[p][1][q] += a[p] * bq1[q];
                }
        }
        __syncthreads();
    }
    float* basep = dgp + (size_t)blockIdx.z * BB * NE;
    int c1 = e0 + tx * 4, c2 = e0 + 64 + tx * 4;
#pragma unroll
    for (int p = 0; p < 4; p++) {
        int row = b0 + ty * 4 + p;
        if (c1 < NE)
            *(float4*)&basep[row * NE + c1] =
                make_float4(acc[p][0][0], acc[p][0][1], acc[p][0][2], acc[p][0][3]);
        if (c2 < NE)
            *(float4*)&basep[row * NE + c2] =
                make_float4(acc[p][1][0], acc[p][1][1], acc[p][1][2], acc[p][1][3]);
    }
}

// pure LIF phase: block = batch row. writes A1s = NU_PRE*ret1, A2s = NU_POST*(spk*ret2)
__global__ __launch_bounds__(512) void k_mid(const float* __restrict__ dgp,
                                             const float* __restrict__ d,
                                             float* g_ine, float* g_ei, float* g_ie,
                                             float* Iie, float* mem_e, float* rc_e,
                                             float* mem_i, float* rc_i, float* theta,
                                             float* tp1, float* tp2,
                                             float* __restrict__ A1s,
                                             float* __restrict__ A2s,
                                             float* __restrict__ out_t) {
    int b = blockIdx.x;
    int e = threadIdx.x;
    __shared__ float red[8];
    int idx = b * NE + e;

    float spk_i = 0.f, spk_e = 0.f;
    float g1 = 0.f, me = 0.f, re = 0.f, th = 0.f, g2 = 0.f, mi = 0.f, ri = 0.f;

    if (e < NE) {
        float dg = 0.f;
#pragma unroll
        for (int c = 0; c < KC1; c++) dg += dgp[(size_t)c * BB * NE + idx];
        dg = dg / d[e];
        g1 = g_ine[idx]; me = mem_e[idx]; re = rc_e[idx];
        th = theta[idx];
        float Ii = Iie[idx];
        float I_in = g1 * (0.0f - me);
        g1 = g1 + (dg - g1) * C_GSE;
        bool act = (re <= 0.0f);
        float I = I_in + Ii;
        if (act) me = me + ((-65.0f - me) + I) * C_KE;
        re = fmaxf(re - 0.5f, 0.0f);
        float thr = -72.0f + th;
        spk_e = (act && (me > thr)) ? 1.0f : 0.0f;
        if (spk_e > 0.0f) { me = -65.0f; re = 5.0f; }
        float dgei = spk_e * 10.4f;
        g2 = g_ei[idx]; mi = mem_i[idx]; ri = rc_i[idx];
        float I_ei = g2 * (0.0f - mi);
        g2 = g2 + (dgei - g2) * C_GSE;
        bool ai = (ri <= 0.0f);
        if (ai) mi = mi + ((-60.0f - mi) + I_ei) * C_KI;
        ri = fmaxf(ri - 0.5f, 0.0f);
        spk_i = (ai && (mi > -40.0f)) ? 1.0f : 0.0f;
        if (spk_i > 0.0f) { mi = -45.0f; ri = 2.0f; }
    }
    float v = spk_i;
#pragma unroll
    for (int o = 32; o > 0; o >>= 1) v += __shfl_down(v, o, 64);
    if ((e & 63) == 0) red[e >> 6] = v;
    __syncthreads();
    float S = ((red[0] + red[1]) + (red[2] + red[3])) +
              ((red[4] + red[5]) + (red[6] + red[7]));   // integer-valued: exact
    if (e < NE) {
        float dgie = 17.0f * (S - spk_i);
        float g3 = g_ie[idx];
        float Iie_new = g3 * (-100.0f - me);
        g3 = g3 + (dgie - g3) * C_GSI;
        float th2 = th * C_DECTH + 0.05f * spk_e;
        float r1 = tp1[idx] * C_DEC1;
        float r2 = tp2[idx] * C_DEC2;
        bool fired = spk_e > 0.9f;
        A1s[idx] = C_NUPRE * r1;
        A2s[idx] = C_NUPOST * (spk_e * r2);
        tp1[idx] = fired ? 1.0f : r1;
        tp2[idx] = fired ? 1.0f : r2;
        g_ine[idx] = g1; g_ei[idx] = g2; g_ie[idx] = g3; Iie[idx] = Iie_new;
        mem_e[idx] = me; rc_e[idx] = re; mem_i[idx] = mi; rc_i[idx] = ri;
        theta[idx] = th2;
        out_t[idx] = spk_e;
    }
}

// gemm2 concat: part[c][e][i] = sum_{k in chunk} At[k,e]*Xt[k,i]
// At = [NU_PRE*A1 ; NU_POST*A2spk] (1024 x 400), Xt = [x ; tr] (1024 x 784)
// tile 64(e) x 128(i), per-thread 4x8 quadrants, k-tile 16, chunk 64
__global__ __launch_bounds__(256) void k_g2(const float* __restrict__ A1s,
                                            const float* __restrict__ A2s,
                                            const float* __restrict__ x,
                                            const float* __restrict__ tr,
                                            float* __restrict__ part) {
    __shared__ float sA[16][68];    // [k][e 64]
    __shared__ float sB[16][132];   // [k][i 128]
    const int lid = threadIdx.x;
    const int tx = lid & 15, ty = lid >> 4;
    const int e0 = blockIdx.x * 64, i0 = blockIdx.y * 128;
    const int kb = blockIdx.z * KCH2;
    const int kr = lid >> 4;            // 0..15 (k row)
    const int jc = (lid & 15) * 4;      // col offset 0..60
    const float4 z4 = make_float4(0.f, 0.f, 0.f, 0.f);

    float acc[4][2][4];
#pragma unroll
    for (int p = 0; p < 4; p++)
#pragma unroll
        for (int h = 0; h < 2; h++)
#pragma unroll
            for (int q = 0; q < 4; q++) acc[p][h][q] = 0.f;

    float4 av_, bv0_, bv1_;
    auto ld = [&](int kt) {
        int gb = kb + kt * 16 + kr;
        int ec = e0 + jc;
        if (ec < NE)
            av_ = (gb < BB) ? *(const float4*)&A1s[gb * NE + ec]
                            : *(const float4*)&A2s[(gb - BB) * NE + ec];
        else av_ = z4;
        const float* src; int rb;
        if (gb < BB) { src = x; rb = gb; } else { src = tr; rb = gb - BB; }
        int c1 = i0 + jc, c2 = i0 + 64 + jc;
        bv0_ = (c1 < NIN) ? *(const float4*)&src[rb * NIN + c1] : z4;
        bv1_ = (c2 < NIN) ? *(const float4*)&src[rb * NIN + c2] : z4;
    };

    ld(0);
    for (int kt = 0; kt < KCH2 / 16; kt++) {
        *(float4*)&sA[kr][jc] = av_;
        *(float4*)&sB[kr][jc] = bv0_;
        *(float4*)&sB[kr][64 + jc] = bv1_;
        __syncthreads();
        if (kt < KCH2 / 16 - 1) ld(kt + 1);
#pragma unroll
        for (int k = 0; k < 16; k++) {
            float4 av = *(const float4*)&sA[k][ty * 4];
            float4 b0v = *(const float4*)&sB[k][tx * 4];
            float4 b1v = *(const float4*)&sB[k][64 + tx * 4];
            float a[4] = {av.x, av.y, av.z, av.w};
            float bq0[4] = {b0v.x, b0v.y, b0v.z, b0v.w};
            float bq1[4] = {b1v.x, b1v.y, b1v.z, b1v.w};
#pragma unroll
            for (int p = 0; p < 4; p++)
#pragma unroll
                for (int q = 0; q < 4; q++) {
                    acc[p][0][q] += a[p] * bq0[q];
                    acc[p][1][q] += a[p] * bq1[q];
                }
        }
        __syncthreads();
    }
    float* basep = part + (size_t)blockIdx.z * NE * NIN;
    int c1 = i0 + tx * 4, c2 = i0 + 64 + tx * 4;
#pragma unroll
    for (int p = 0; p < 4; p++) {
        int row = e0 + ty * 4 + p;
        if (row < NE) {
            if (c1 < NIN)
                *(float4*)&basep[row * NIN + c1] =
                    make_float4(acc[p][0][0], acc[p][0][1], acc[p][0][2], acc[p][0][3]);
            if (c2 < NIN)
                *(float4*)&basep[row * NIN + c2] =
                    make_float4(acc[p][1][0], acc[p][1][1], acc[p][1][2], acc[p][1][3]);
        }
    }
}

// blocks [0,400): W update + rowsum ; blocks [400,596): pre-trace for NEXT step
__global__ __launch_bounds__(256) void k_wup(float* __restrict__ W,
                                             const float* __restrict__ part,
                                             float* __restrict__ d,
                                             const float* __restrict__ x1,
                                             float* __restrict__ tr) {
    int bid = blockIdx.x, tid = threadIdx.x;
    if (bid >= NE) {
        int base = (bid - NE) * 2048 + tid * 4;
        float4 xv = *(const float4*)&x1[base];
        float4 tv = *(const float4*)&tr[base];
        float4 o;
        o.x = (xv.x > 0.9f) ? 1.f : tv.x * C_DECPRE;
        o.y = (xv.y > 0.9f) ? 1.f : tv.y * C_DECPRE;
        o.z = (xv.z > 0.9f) ? 1.f : tv.z * C_DECPRE;
        o.w = (xv.w > 0.9f) ? 1.f : tv.w * C_DECPRE;
        *(float4*)&tr[base] = o;
        return;
    }
    __shared__ float red[256];
    float dv = d[bid];
    float s = 0.f;
    if (tid < 196) {
        int off = bid * NIN + tid * 4;
        float4 w = *(const float4*)&W[off];
        float4 acc = make_float4(w.x / dv, w.y / dv, w.z / dv, w.w / dv);
#pragma unroll
        for (int c = 0; c < KC2; c++) {
            float4 p = *(const float4*)&part[(size_t)c * NE * NIN + off];
            acc.x += p.x; acc.y += p.y; acc.z += p.z; acc.w += p.w;
        }
        acc.x = fminf(fmaxf(acc.x, 0.f), 1.f);
        acc.y = fminf(fmaxf(acc.y, 0.f), 1.f);
        acc.z = fminf(fmaxf(acc.z, 0.f), 1.f);
        acc.w = fminf(fmaxf(acc.w, 0.f), 1.f);
        *(float4*)&W[off] = acc;
        s = acc.x + acc.y + acc.z + acc.w;
    }
    red[tid] = s;
    __syncthreads();
    for (int off = 128; off > 0; off >>= 1) {
        if (tid < off) red[tid] += red[tid + off];
        __syncthreads();
    }
    if (tid == 0) d[bid] = red[0] / 78.4f;
}

extern "C" void kernel_launch(void* const* d_in, const int* in_sizes, int n_in,
                              void* d_out, int out_size, void* d_ws, size_t ws_size,
                              hipStream_t stream) {
    const float* x     = (const float*)d_in[0];  // (50, 512, 784)
    const float* W_ine = (const float*)d_in[1];  // (400, 784)

    float* p = (float*)d_ws;
    float* W_cur = p; p += NE * NIN;
    float* dbuf  = p; p += NE;
    float* dgp   = p; p += (size_t)KC1 * BB * NE;
    float* part  = p; p += (size_t)KC2 * NE * NIN;
    float* A1s   = p; p += BB * NE;
    float* A2s   = p; p += BB * NE;
    float* g_ine = p; p += BB * NE;
    float* g_ei  = p; p += BB * NE;
    float* g_ie  = p; p += BB * NE;
    float* Iie   = p; p += BB * NE;
    float* mem_e = p; p += BB * NE;
    float* rc_e  = p; p += BB * NE;
    float* mem_i = p; p += BB * NE;
    float* rc_i  = p; p += BB * NE;
    float* theta = p; p += BB * NE;
    float* tp1   = p; p += BB * NE;
    float* tp2   = p; p += BB * NE;
    float* tr    = p; p += BB * NIN;

    hipMemcpyAsync(W_cur, W_ine, (size_t)NE * NIN * sizeof(float),
                   hipMemcpyDeviceToDevice, stream);
    k_init<<<(BB * NE + 255) / 256, 256, 0, stream>>>(g_ine, g_ei, g_ie, Iie, mem_e,
                                                      rc_e, mem_i, rc_i, theta, tp1, tp2);
    k_pre<<<NE + 196, 256, 0, stream>>>(W_cur, dbuf, x, tr);

    for (int t = 0; t < TT; t++) {
        const float* xt = x + (size_t)t * BB * NIN;
        float* out_t = (float*)d_out + (size_t)t * BB * NE;
        k_g1<<<dim3(4, 8, KC1), 256, 0, stream>>>(xt, W_cur, dgp);
        k_mid<<<BB, 512, 0, stream>>>(dgp, dbuf, g_ine, g_ei, g_ie,
                                      Iie, mem_e, rc_e, mem_i, rc_i, theta,
                                      tp1, tp2, A1s, A2s, out_t);
        if (t < TT - 1) {
            k_g2<<<dim3(7, 7, KC2), 256, 0, stream>>>(A1s, A2s, xt, tr, part);
            k_wup<<<NE + 196, 256, 0, stream>>>(W_cur, part, dbuf,
                                                xt + (size_t)BB * NIN, tr);
        }
    }
}